// Round 3
// baseline (1094.888 us; speedup 1.0000x reference)
//
#include <hip/hip_runtime.h>
#include <hip/hip_bf16.h>
#include <cstdint>
#include <cstddef>

typedef __attribute__((ext_vector_type(8))) short short8;   // 8 bf16 = 4 VGPRs (MFMA A/B frag)
typedef __attribute__((ext_vector_type(4))) float f32x4;    // MFMA C/D frag

__device__ __forceinline__ unsigned short f2bf(float f) {
  unsigned u = __float_as_uint(f);
  unsigned r = (u + 0x7fffu + ((u >> 16) & 1u)) >> 16;   // RNE
  return (unsigned short)r;
}
__device__ __forceinline__ float bf2f(unsigned short b) {
  return __uint_as_float(((unsigned)b) << 16);
}
// order-preserving float -> uint key for atomicMax (0 sentinel < every real key)
__device__ __forceinline__ unsigned fkey(float f) {
  unsigned b = __float_as_uint(f);
  return (b & 0x80000000u) ? ~b : (b | 0x80000000u);
}

// ---------------------------------------------------------------------------
// Pack W1a [256(k) x 256(col)] fp32 -> bf16 in MFMA-B-fragment order:
// packedB[((s*32 + kk*4+quad)*64 + n)*8 + j] = bf16(W1a[kk*32+quad*8+j][s*64+n])
// (s = col>>6, n = col&63, k = kk*32+quad*8+j). Reads coalesced (col fastest).
// ---------------------------------------------------------------------------
__global__ __launch_bounds__(256)
void prep_b_kernel(const float* __restrict__ W1a, unsigned short* __restrict__ packedB) {
  int idx = blockIdx.x * 256 + threadIdx.x;   // 0..65535
  int col = idx & 255;
  int k   = idx >> 8;
  int s = col >> 6, n = col & 63;
  int kk = k >> 5, r = k & 31;
  int quad = r >> 3, j = r & 7;
  packedB[(size_t)(((s * 32 + kk * 4 + quad) * 64 + n) * 8 + j)] = f2bf(W1a[idx]);
}

// ---------------------------------------------------------------------------
// Persistent fused phase-A: bf16 MFMA GEMM (x @ W1a) -> relu -> @W2a -> sigmoid
// -> aw, then segment pooling via atomics. W1a fragments live in REGISTERS
// (wave w owns hidden cols [w*64, w*64+64): 8kk x 4nb frags = 32 VGPRs).
// 1024 blocks (4/CU: VGPR<=128, LDS 35.4KB*4=141KB) loop over 64-node tiles.
// ---------------------------------------------------------------------------
__global__ __launch_bounds__(256, 4)
void phase_a_kernel(const float* __restrict__ x, const int* __restrict__ batch,
                    const unsigned short* __restrict__ packedB,
                    const float* __restrict__ b1a, const float* __restrict__ W2a,
                    const float* __restrict__ b2a,
                    float* __restrict__ attbuf, float* __restrict__ sumbuf,
                    unsigned* __restrict__ maxkey, float* __restrict__ cntbuf,
                    int nnodes, int ntiles) {
  __shared__ __align__(16) unsigned short sX[64][264];   // bf16 x tile, +8 pad/row
  __shared__ float sScoreP[4][64];                       // per-wave score partials
  __shared__ float sAw[64];
  __shared__ int   sBatch[64];

  const int t = threadIdx.x;
  const int lane = t & 63;
  const int w = t >> 6;          // wave id: owns hidden cols w*64 .. w*64+63
  const int m = lane & 15;
  const int quad = lane >> 4;

  // --- resident B fragments (once per block; L2-hot) ---
  short8 Bfrag[8][4];
  #pragma unroll
  for (int kk = 0; kk < 8; ++kk) {
    #pragma unroll
    for (int nb = 0; nb < 4; ++nb) {
      Bfrag[kk][nb] = *reinterpret_cast<const short8*>(
          packedB + (size_t)((w * 32 + kk * 4 + quad) * 64 + nb * 16 + m) * 8);
    }
  }
  float b1r[4], w2r[4];
  #pragma unroll
  for (int nb = 0; nb < 4; ++nb) {
    int col = w * 64 + nb * 16 + m;
    b1r[nb] = b1a[col];
    w2r[nb] = W2a[col];
  }
  const float b2 = b2a[0];

  for (int tile = blockIdx.x; tile < ntiles; tile += gridDim.x) {
    const int block0 = tile * 64;
    const int nvalid = min(64, nnodes - block0);

    // pad invalid rows with the LAST node's segment id (batch sorted) so the
    // constant-trip pooling loop never flushes to a bogus segment.
    if (t < 64) sBatch[t] = batch[min(block0 + t, nnodes - 1)];

    // stage x tile (64 x 256 fp32) -> bf16 LDS, coalesced float4 loads
    #pragma unroll
    for (int it = 0; it < 16; ++it) {
      int idx = it * 256 + t;       // float4 slot 0..4095
      int row = idx >> 6;
      int c4  = idx & 63;
      float4 v = make_float4(0.f, 0.f, 0.f, 0.f);
      if (block0 + row < nnodes)
        v = reinterpret_cast<const float4*>(x)[(size_t)(block0 + row) * 64 + c4];
      ushort4 h;
      h.x = f2bf(v.x); h.y = f2bf(v.y); h.z = f2bf(v.z); h.w = f2bf(v.w);
      *reinterpret_cast<ushort4*>(&sX[row][c4 * 4]) = h;
    }
    __syncthreads();

    // MFMA: wave w computes h[:, w*64 : w*64+64] for all 64 nodes, folds into
    // partial attention scores.
    #pragma unroll
    for (int mt = 0; mt < 4; ++mt) {
      f32x4 acc[4] = {{0,0,0,0},{0,0,0,0},{0,0,0,0},{0,0,0,0}};
      #pragma unroll
      for (int kk = 0; kk < 8; ++kk) {
        short8 af = *reinterpret_cast<const short8*>(&sX[mt * 16 + m][kk * 32 + quad * 8]);
        #pragma unroll
        for (int nb = 0; nb < 4; ++nb)
          acc[nb] = __builtin_amdgcn_mfma_f32_16x16x32_bf16(af, Bfrag[kk][nb], acc[nb], 0, 0, 0);
      }
      float p[4];
      #pragma unroll
      for (int r = 0; r < 4; ++r) {
        float s = 0.f;
        #pragma unroll
        for (int nb = 0; nb < 4; ++nb)
          s += fmaxf(acc[nb][r] + b1r[nb], 0.f) * w2r[nb];
        p[r] = s;
      }
      #pragma unroll
      for (int off = 1; off < 16; off <<= 1) {
        #pragma unroll
        for (int r = 0; r < 4; ++r) p[r] += __shfl_xor(p[r], off, 64);
      }
      if (m == 0) {
        #pragma unroll
        for (int r = 0; r < 4; ++r) sScoreP[w][mt * 16 + quad * 4 + r] = p[r];
      }
    }
    __syncthreads();

    if (t < 64) {
      float s = sScoreP[0][t] + sScoreP[1][t] + sScoreP[2][t] + sScoreP[3][t] + b2;
      sAw[t] = 1.f / (1.f + __expf(-s));
    }
    __syncthreads();

    // segment pooling: thread t owns channel t; batch sorted -> run-length
    // flush. CONSTANT trip count 64 so the LDS reads unroll & batch; invalid
    // rows contribute 0 to sum/att, -inf to max, 0 to count.
    float a_att = 0.f, a_sum = 0.f, a_max = -INFINITY;
    int seg = sBatch[0];
    int runlen = 0;
    #pragma unroll 16
    for (int i = 0; i < 64; ++i) {
      int b = sBatch[i];
      if (b != seg) {
        atomicAdd(&attbuf[(size_t)seg * 256 + t], a_att);
        atomicAdd(&sumbuf[(size_t)seg * 256 + t], a_sum);
        atomicMax(&maxkey[(size_t)seg * 256 + t], fkey(a_max));
        if (t == 0) atomicAdd(&cntbuf[seg], (float)runlen);
        a_att = 0.f; a_sum = 0.f; a_max = -INFINITY; runlen = 0; seg = b;
      }
      bool valid = (i < nvalid);
      float xv = bf2f(sX[i][t]);
      float xs = valid ? xv : 0.f;
      a_sum += xs;
      a_att += xs * sAw[i];
      a_max = fmaxf(a_max, valid ? xv : -INFINITY);
      runlen += valid ? 1 : 0;
    }
    atomicAdd(&attbuf[(size_t)seg * 256 + t], a_att);
    atomicAdd(&sumbuf[(size_t)seg * 256 + t], a_sum);
    atomicMax(&maxkey[(size_t)seg * 256 + t], fkey(a_max));
    if (t == 0) atomicAdd(&cntbuf[seg], (float)runlen);
    __syncthreads();   // protect sX/sBatch before next tile's staging
  }
}

// ---------------------------------------------------------------------------
// Final MLP: out[g] = relu(comb[g] @ W1f + b1f) @ W2f + b2f, 4 graphs/block
// (1024 blocks -> good latency hiding), rank-1-update formulation.
// ---------------------------------------------------------------------------
__global__ __launch_bounds__(256, 4)
void final_mlp_kernel(const float* __restrict__ attbuf, const float* __restrict__ sumbuf,
                      const unsigned* __restrict__ maxkey, const float* __restrict__ cntbuf,
                      const float* __restrict__ W1f, const float* __restrict__ b1f,
                      const float* __restrict__ W2f, const float* __restrict__ b2f,
                      float* __restrict__ out) {
  __shared__ float sComb[4 * 768];
  __shared__ float sHid[4 * 256];
  const int t = threadIdx.x;
  const int g0 = blockIdx.x * 4;

  for (int idx = t; idx < 4 * 768; idx += 256) {
    int g = idx / 768;
    int k = idx - g * 768;
    int gg = g0 + g;
    float cnt = cntbuf[gg];
    float v;
    if (k < 256) {
      v = attbuf[(size_t)gg * 256 + k];
    } else if (k < 512) {
      v = sumbuf[(size_t)gg * 256 + (k - 256)] / fmaxf(cnt, 1.f);
    } else {
      unsigned u = maxkey[(size_t)gg * 256 + (k - 512)];
      unsigned b = (u & 0x80000000u) ? (u & 0x7fffffffu) : ~u;
      v = (cnt > 0.f) ? __uint_as_float(b) : 0.f;   // empty segment -> 0
    }
    sComb[idx] = v;
  }
  __syncthreads();

  float acc[4] = {0, 0, 0, 0};
  #pragma unroll 4
  for (int k = 0; k < 768; ++k) {
    float wv = W1f[k * 256 + t];
    #pragma unroll
    for (int g = 0; g < 4; ++g) acc[g] = fmaf(sComb[g * 768 + k], wv, acc[g]);
  }
  float bb = b1f[t];
  #pragma unroll
  for (int g = 0; g < 4; ++g) sHid[g * 256 + t] = fmaxf(acc[g] + bb, 0.f);
  __syncthreads();

  float acc2[4] = {0, 0, 0, 0};
  #pragma unroll 4
  for (int k = 0; k < 256; ++k) {
    float wv = W2f[k * 256 + t];
    #pragma unroll
    for (int g = 0; g < 4; ++g) acc2[g] = fmaf(sHid[g * 256 + k], wv, acc2[g]);
  }
  float bo = b2f[t];
  #pragma unroll
  for (int g = 0; g < 4; ++g) out[(size_t)(g0 + g) * 256 + t] = acc2[g] + bo;
}

// ---------------------------------------------------------------------------
extern "C" void kernel_launch(void* const* d_in, const int* in_sizes, int n_in,
                              void* d_out, int out_size, void* d_ws, size_t ws_size,
                              hipStream_t stream) {
  const float* x   = (const float*)d_in[0];
  const int* batch = (const int*)d_in[1];
  const float* W1a = (const float*)d_in[2];
  const float* b1a = (const float*)d_in[3];
  const float* W2a = (const float*)d_in[4];
  const float* b2a = (const float*)d_in[5];
  const float* W1f = (const float*)d_in[6];
  const float* b1f = (const float*)d_in[7];
  const float* W2f = (const float*)d_in[8];
  const float* b2f = (const float*)d_in[9];
  float* out = (float*)d_out;

  const int N = in_sizes[0] / 256;
  const int G = out_size / 256;

  char* ws = (char*)d_ws;
  float* attbuf = (float*)ws;
  float* sumbuf = attbuf + (size_t)G * 256;
  unsigned* maxkey = (unsigned*)(sumbuf + (size_t)G * 256);
  float* cntbuf = (float*)(maxkey + (size_t)G * 256);
  unsigned short* packedB = (unsigned short*)(cntbuf + G);

  size_t zero_bytes = ((size_t)G * 256 * 3 + G) * sizeof(float);
  hipMemsetAsync(d_ws, 0, zero_bytes, stream);

  prep_b_kernel<<<256, 256, 0, stream>>>(W1a, packedB);

  int ntiles = (N + 63) / 64;
  phase_a_kernel<<<1024, 256, 0, stream>>>(x, batch, packedB, b1a, W2a, b2a,
                                           attbuf, sumbuf, maxkey, cntbuf, N, ntiles);

  final_mlp_kernel<<<G / 4, 256, 0, stream>>>(attbuf, sumbuf, maxkey, cntbuf,
                                              W1f, b1f, W2f, b2f, out);
}